// Round 11
// baseline (273.807 us; speedup 1.0000x reference)
//
#include <hip/hip_runtime.h>

#define F_DIM 128
#define NG 3
#define XCDS 8
#define BEPT 16      // edges per thread in build (batched-atomic version)
#define CAP 48       // fixed per-node CSR capacity (mean deg 16, max ~35)
#define SPILL_CAP 8192

typedef __attribute__((ext_vector_type(8))) short short8_t;
typedef __attribute__((ext_vector_type(4))) float f32x4;

__device__ __forceinline__ unsigned short f2bf(float f) {
    unsigned int x = __float_as_uint(f);
    unsigned int r = x + 0x7fffu + ((x >> 16) & 1u);  // RNE
    return (unsigned short)(r >> 16);
}
__device__ __forceinline__ float bflo(unsigned int u) { return __uint_as_float(u << 16); }
__device__ __forceinline__ float bfhi(unsigned int u) { return __uint_as_float(u & 0xffff0000u); }

struct GArgs {
    const int* src[NG]; const int* dst[NG];
    const float* X[NG]; const float* W[NG]; const float* b[NG];
    float* out[NG];
    unsigned short* Xps[NG];  // bf16 row-major [N][128], pre-scaled by dinv[row]
    int* cursor[NG];          // [N] bucket cursors (init i*CAP)
    int* cstore[NG];          // [N] stored counts (<=CAP)
    float* dinv[NG];          // [N]
    int* sorted[NG];          // [N*CAP]
    int* spill[NG];           // [SPILL_CAP*2] (src,dst) pairs
    int* spill_n[NG];         // [1]
};

// ---- init: cursor[i] = i*CAP; spill_n = 0 ------------------------------------
__global__ __launch_bounds__(256) void init_kernel(GArgs a, int g0, int n) {
    int g = g0 + blockIdx.y;
    int i = blockIdx.x * 256 + threadIdx.x;
    if (i < n) a.cursor[g][i] = i * CAP;
    if (i == 0) a.spill_n[g][0] = 0;
}

// ---- bucket-scatter, XCD-partitioned, batched atomics (MLP=BEPT) -------------
// Phase 1: load all dst/src (NT). Phase 2: issue all predicated atomics
// back-to-back (independent). Phase 3: drain once, do all stores.
__global__ __launch_bounds__(256) void build_kernel(GArgs a, int g0, int E, int nPerX) {
    int g = g0 + blockIdx.y;
    int xcd = blockIdx.x % XCDS;
    int lo = xcd * nPerX, hi = lo + nPerX;
    const int* dst = a.dst[g];
    const int* src = a.src[g];
    int* cursor = a.cursor[g];
    int* sorted = a.sorted[g];
    int base = (blockIdx.x / XCDS) * (256 * BEPT) + threadIdx.x;

    int d[BEPT], sv[BEPT], p[BEPT];
    bool m[BEPT];
#pragma unroll
    for (int i = 0; i < BEPT; ++i) {
        int e = base + i * 256;
        bool valid = e < E;
        int ec = valid ? e : 0;
        d[i] = __builtin_nontemporal_load(&dst[ec]);
        sv[i] = __builtin_nontemporal_load(&src[ec]);
        m[i] = valid && (d[i] >= lo) && (d[i] < hi);
    }
#pragma unroll
    for (int i = 0; i < BEPT; ++i) {
        if (m[i]) p[i] = atomicAdd(&cursor[d[i]], 1);
    }
#pragma unroll
    for (int i = 0; i < BEPT; ++i) {
        if (m[i]) {
            if (p[i] < d[i] * CAP + CAP) {
                sorted[p[i]] = sv[i];
            } else {
                int sp = atomicAdd(a.spill_n[g], 1);
                if (sp < SPILL_CAP) {
                    a.spill[g][2 * sp] = sv[i];
                    a.spill[g][2 * sp + 1] = d[i];
                }
            }
        }
    }
}

// ---- counts + dinv from cursors ----------------------------------------------
__global__ __launch_bounds__(256) void counts_kernel(GArgs a, int g0, int n) {
    int g = g0 + blockIdx.y;
    int i = blockIdx.x * 256 + threadIdx.x;
    if (i >= n) return;
    int deg = a.cursor[g][i] - i * CAP;
    a.cstore[g][i] = min(deg, CAP);
    a.dinv[g][i] = rsqrtf((float)deg + 1.0f);
}

// ---- MFMA bf16 GEMM: Xps(bf16 row-major) = dinv[row] * (X @ W + b) -----------
__global__ __launch_bounds__(256) void gemm_kernel(GArgs a, int g0, int n) {
    int g = g0 + blockIdx.y;
    __shared__ unsigned short Xl[128 * 128];
    __shared__ unsigned short Wt[128 * 128];
    const int t = threadIdx.x;
    const int row0 = blockIdx.x * 128;
    const float* X = a.X[g];
    const float* W = a.W[g];
    char* XlB = (char*)Xl;
    char* WtB = (char*)Wt;

    for (int i = t; i < 128 * 16; i += 256) {
        int r = i >> 4, kc = i & 15;
        int row = row0 + r;
        float4 x0 = make_float4(0.f, 0.f, 0.f, 0.f), x1 = x0;
        if (row < n) {
            const float4* xp = (const float4*)(X + (size_t)row * F_DIM + kc * 8);
            x0 = xp[0]; x1 = xp[1];
        }
        uint4 pk;
        pk.x = (unsigned)f2bf(x0.x) | ((unsigned)f2bf(x0.y) << 16);
        pk.y = (unsigned)f2bf(x0.z) | ((unsigned)f2bf(x0.w) << 16);
        pk.z = (unsigned)f2bf(x1.x) | ((unsigned)f2bf(x1.y) << 16);
        pk.w = (unsigned)f2bf(x1.z) | ((unsigned)f2bf(x1.w) << 16);
        unsigned int ad = (unsigned)((r << 8) + (kc << 4)) ^ (unsigned)((r & 15) << 4);
        *(uint4*)(XlB + ad) = pk;
    }
    for (int i = t; i < 128 * 16; i += 256) {
        int nn = i & 127, kc = i >> 7;
        const float* wp = W + (size_t)(kc * 8) * F_DIM + nn;
        uint4 pk;
        pk.x = (unsigned)f2bf(wp[0])   | ((unsigned)f2bf(wp[128]) << 16);
        pk.y = (unsigned)f2bf(wp[256]) | ((unsigned)f2bf(wp[384]) << 16);
        pk.z = (unsigned)f2bf(wp[512]) | ((unsigned)f2bf(wp[640]) << 16);
        pk.w = (unsigned)f2bf(wp[768]) | ((unsigned)f2bf(wp[896]) << 16);
        unsigned int ad = (unsigned)((nn << 8) + (kc << 4)) ^ (unsigned)((nn & 15) << 4);
        *(uint4*)(WtB + ad) = pk;
    }
    __syncthreads();

    const int l = t & 63;
    const int wv = t >> 6;
    const int wr = wv >> 1, wc = wv & 1;
    const int lm = l & 15;
    const int lk = l >> 4;

    f32x4 acc[4][4] = {};
#pragma unroll
    for (int ks = 0; ks < 4; ++ks) {
        const int kb = ks * 64 + lk * 16;
        short8_t af[4], bv[4];
#pragma unroll
        for (int mt = 0; mt < 4; ++mt) {
            int r = wr * 64 + mt * 16 + lm;
            unsigned int ad = (unsigned)((r << 8) + kb) ^ (unsigned)((r & 15) << 4);
            af[mt] = *(const short8_t*)(XlB + ad);
        }
#pragma unroll
        for (int nt = 0; nt < 4; ++nt) {
            int c = wc * 64 + nt * 16 + lm;
            unsigned int ad = (unsigned)((c << 8) + kb) ^ (unsigned)((c & 15) << 4);
            bv[nt] = *(const short8_t*)(WtB + ad);
        }
#pragma unroll
        for (int mt = 0; mt < 4; ++mt)
#pragma unroll
            for (int nt = 0; nt < 4; ++nt)
                acc[mt][nt] = __builtin_amdgcn_mfma_f32_16x16x32_bf16(af[mt], bv[nt],
                                                                      acc[mt][nt], 0, 0, 0);
    }

    const float* bia = a.b[g];
    const float* dinv = a.dinv[g];
    unsigned short* Xps = a.Xps[g];
#pragma unroll
    for (int nt = 0; nt < 4; ++nt) {
        int col = wc * 64 + nt * 16 + lm;
        float bc = bia[col];
#pragma unroll
        for (int mt = 0; mt < 4; ++mt) {
            int rbase = row0 + wr * 64 + mt * 16 + lk * 4;
#pragma unroll
            for (int r = 0; r < 4; ++r) {
                int row = rbase + r;
                if (row < n) {
                    float v = (acc[mt][nt][r] + bc) * dinv[row];
                    Xps[(size_t)row * F_DIM + col] = f2bf(v);
                }
            }
        }
    }
}

// ---- aggregation: one wave per node; 8-deep batched gathers (MLP=8) ----------
__global__ __launch_bounds__(256) void agg_kernel(GArgs a, int g0, int n) {
    int g = g0 + blockIdx.y;
    int wave = (blockIdx.x * 256 + threadIdx.x) >> 6;
    if (wave >= n) return;
    int lane = threadIdx.x & 63;
    const unsigned int* Xp = (const unsigned int*)a.Xps[g];  // 64 u32 per row
    const int* sorted = a.sorted[g];
    int beg = wave * CAP;
    int cnt = a.cstore[g][wave];
    unsigned int u0 = Xp[(size_t)wave * 64 + lane];
    float ax = bflo(u0), ay = bfhi(u0);
    for (int j = 0; j < cnt;) {
        int m = min(cnt - j, 64);
        int s = (j + lane < cnt) ? __builtin_nontemporal_load(&sorted[beg + j + lane]) : 0;
        int k = 0;
        for (; k + 8 <= m; k += 8) {
            int s0 = __shfl(s, k + 0, 64), s1 = __shfl(s, k + 1, 64);
            int s2 = __shfl(s, k + 2, 64), s3 = __shfl(s, k + 3, 64);
            int s4 = __shfl(s, k + 4, 64), s5 = __shfl(s, k + 5, 64);
            int s6 = __shfl(s, k + 6, 64), s7 = __shfl(s, k + 7, 64);
            unsigned int v0 = Xp[(size_t)s0 * 64 + lane];
            unsigned int v1 = Xp[(size_t)s1 * 64 + lane];
            unsigned int v2 = Xp[(size_t)s2 * 64 + lane];
            unsigned int v3 = Xp[(size_t)s3 * 64 + lane];
            unsigned int v4 = Xp[(size_t)s4 * 64 + lane];
            unsigned int v5 = Xp[(size_t)s5 * 64 + lane];
            unsigned int v6 = Xp[(size_t)s6 * 64 + lane];
            unsigned int v7 = Xp[(size_t)s7 * 64 + lane];
            ax += bflo(v0); ay += bfhi(v0);
            ax += bflo(v1); ay += bfhi(v1);
            ax += bflo(v2); ay += bfhi(v2);
            ax += bflo(v3); ay += bfhi(v3);
            ax += bflo(v4); ay += bfhi(v4);
            ax += bflo(v5); ay += bfhi(v5);
            ax += bflo(v6); ay += bfhi(v6);
            ax += bflo(v7); ay += bfhi(v7);
        }
        if (k + 4 <= m) {
            int s0 = __shfl(s, k + 0, 64), s1 = __shfl(s, k + 1, 64);
            int s2 = __shfl(s, k + 2, 64), s3 = __shfl(s, k + 3, 64);
            unsigned int v0 = Xp[(size_t)s0 * 64 + lane];
            unsigned int v1 = Xp[(size_t)s1 * 64 + lane];
            unsigned int v2 = Xp[(size_t)s2 * 64 + lane];
            unsigned int v3 = Xp[(size_t)s3 * 64 + lane];
            ax += bflo(v0); ay += bfhi(v0);
            ax += bflo(v1); ay += bfhi(v1);
            ax += bflo(v2); ay += bfhi(v2);
            ax += bflo(v3); ay += bfhi(v3);
            k += 4;
        }
        for (; k < m; ++k) {
            int sk = __shfl(s, k, 64);
            unsigned int v = Xp[(size_t)sk * 64 + lane];
            ax += bflo(v);
            ay += bfhi(v);
        }
        j += m;
    }
    float dd = a.dinv[g][wave];
    ((float2*)a.out[g])[(size_t)wave * 64 + lane] = make_float2(ax * dd, ay * dd);
}

// ---- spill cleanup: out[d] += dinv[d] * Xps[s] for overflow edges ------------
__global__ __launch_bounds__(128) void spill_kernel(GArgs a, int g0) {
    int g = g0 + blockIdx.y;
    int ns = min(a.spill_n[g][0], SPILL_CAP);
    const unsigned short* Xps = a.Xps[g];
    const float* dinv = a.dinv[g];
    float* out = a.out[g];
    for (int i = blockIdx.x; i < ns; i += gridDim.x) {
        int s = a.spill[g][2 * i];
        int d = a.spill[g][2 * i + 1];
        float w = dinv[d];
        int f = threadIdx.x;
        float v = __uint_as_float(((unsigned int)Xps[(size_t)s * F_DIM + f]) << 16);
        unsafeAtomicAdd(&out[(size_t)d * F_DIM + f], w * v);
    }
}

extern "C" void kernel_launch(void* const* d_in, const int* in_sizes, int n_in,
                              void* d_out, int out_size, void* d_ws, size_t ws_size,
                              hipStream_t stream) {
    const float* Xin[NG] = {(const float*)d_in[0], (const float*)d_in[1], (const float*)d_in[2]};
    const int* ei[NG] = {(const int*)d_in[3], (const int*)d_in[4], (const int*)d_in[5]};
    const float* Wk[NG] = {(const float*)d_in[6], (const float*)d_in[8], (const float*)d_in[10]};
    const float* bk[NG] = {(const float*)d_in[7], (const float*)d_in[9], (const float*)d_in[11]};

    const int N = in_sizes[0] / F_DIM;  // 50000
    const int E = in_sizes[3] / 2;      // 800000
    float* out = (float*)d_out;

    const size_t xps_b = (size_t)N * F_DIM * 2;       // bf16
    const size_t sorted_b = (size_t)N * CAP * 4;
    const size_t nb = (size_t)N * 4;
    const size_t spill_b = (size_t)SPILL_CAP * 8 + 64;
    const size_t per = ((xps_b + sorted_b + 3 * nb + spill_b + 255) / 256) * 256;
    const bool fused = ws_size >= (size_t)NG * per;
    char* base = (char*)d_ws;

    GArgs a;
    for (int r = 0; r < NG; ++r) {
        char* s = base + (size_t)(fused ? r : 0) * per;
        a.Xps[r] = (unsigned short*)s;
        a.sorted[r] = (int*)(s + xps_b);
        a.cursor[r] = (int*)(s + xps_b + sorted_b);
        a.cstore[r] = (int*)(s + xps_b + sorted_b + nb);
        a.dinv[r] = (float*)(s + xps_b + sorted_b + 2 * nb);
        a.spill[r] = (int*)(s + xps_b + sorted_b + 3 * nb);
        a.spill_n[r] = (int*)(s + xps_b + sorted_b + 3 * nb + spill_b - 64);
        a.src[r] = ei[r];
        a.dst[r] = ei[r] + E;
        a.X[r] = Xin[r];
        a.W[r] = Wk[r];
        a.b[r] = bk[r];
        a.out[r] = out + (size_t)r * N * F_DIM;
    }

    const dim3 blk(256);
    const int nPerX = (N + XCDS - 1) / XCDS;
    const int chunks = (E + 256 * BEPT - 1) / (256 * BEPT);
    const int gP = chunks * XCDS;
    const int gN = (N + 255) / 256;
    const int gR = (N + 127) / 128;
    const int gA = (N * 64 + 255) / 256;

    if (fused) {
        init_kernel<<<dim3(gN, NG), blk, 0, stream>>>(a, 0, N);
        build_kernel<<<dim3(gP, NG), blk, 0, stream>>>(a, 0, E, nPerX);
        counts_kernel<<<dim3(gN, NG), blk, 0, stream>>>(a, 0, N);
        gemm_kernel<<<dim3(gR, NG), blk, 0, stream>>>(a, 0, N);
        agg_kernel<<<dim3(gA, NG), blk, 0, stream>>>(a, 0, N);
        spill_kernel<<<dim3(16, NG), dim3(128), 0, stream>>>(a, 0);
    } else {
        for (int g = 0; g < NG; ++g) {
            init_kernel<<<dim3(gN, 1), blk, 0, stream>>>(a, g, N);
            build_kernel<<<dim3(gP, 1), blk, 0, stream>>>(a, g, E, nPerX);
            counts_kernel<<<dim3(gN, 1), blk, 0, stream>>>(a, g, N);
            gemm_kernel<<<dim3(gR, 1), blk, 0, stream>>>(a, g, N);
            agg_kernel<<<dim3(gA, 1), blk, 0, stream>>>(a, g, N);
            spill_kernel<<<dim3(16, 1), dim3(128), 0, stream>>>(a, g);
        }
    }
}

// Round 12
// 265.216 us; speedup vs baseline: 1.0324x; 1.0324x over previous
//
#include <hip/hip_runtime.h>

#define F_DIM 128
#define NG 3
#define XCDS 8
#define EPT 8        // edges per thread in build
#define CAP 48       // fixed per-node CSR capacity (mean deg 16, max ~35)
#define CSTRIDE 16   // cursor padding: one cursor per 64B line (anti-serialization)
#define SPILL_CAP 8192

typedef __attribute__((ext_vector_type(8))) short short8_t;
typedef __attribute__((ext_vector_type(4))) float f32x4;

__device__ __forceinline__ unsigned short f2bf(float f) {
    unsigned int x = __float_as_uint(f);
    unsigned int r = x + 0x7fffu + ((x >> 16) & 1u);  // RNE
    return (unsigned short)(r >> 16);
}
__device__ __forceinline__ float bflo(unsigned int u) { return __uint_as_float(u << 16); }
__device__ __forceinline__ float bfhi(unsigned int u) { return __uint_as_float(u & 0xffff0000u); }

struct GArgs {
    const int* src[NG]; const int* dst[NG];
    const float* X[NG]; const float* W[NG]; const float* b[NG];
    float* out[NG];
    unsigned short* Xps[NG];  // bf16 row-major [N][128], pre-scaled by dinv[row]
    int* cursor[NG];          // [N*CSTRIDE] padded bucket cursors (init i*CAP at i*CSTRIDE)
    int* cstore[NG];          // [N] stored counts (<=CAP)
    float* dinv[NG];          // [N]
    int* sorted[NG];          // [N*CAP]
    int* spill[NG];           // [SPILL_CAP*2] (src,dst) pairs
    int* spill_n[NG];         // [1]
};

// ---- init: cursor[i*CSTRIDE] = i*CAP; spill_n = 0 ----------------------------
__global__ __launch_bounds__(256) void init_kernel(GArgs a, int g0, int n) {
    int g = g0 + blockIdx.y;
    int i = blockIdx.x * 256 + threadIdx.x;
    if (i < n) a.cursor[g][i * CSTRIDE] = i * CAP;
    if (i == 0) a.spill_n[g][0] = 0;
}

// ---- bucket-scatter, XCD-partitioned by dst-range (R8 streaming form) --------
// cursor padded to 1/line: no same-line atomic serialization.
__global__ __launch_bounds__(256) void build_kernel(GArgs a, int g0, int E, int nPerX) {
    int g = g0 + blockIdx.y;
    int xcd = blockIdx.x % XCDS;
    int lo = xcd * nPerX, hi = lo + nPerX;
    const int* dst = a.dst[g];
    const int* src = a.src[g];
    int* cursor = a.cursor[g];
    int* sorted = a.sorted[g];
    int base = (blockIdx.x / XCDS) * (256 * EPT) + threadIdx.x;
#pragma unroll
    for (int i = 0; i < EPT; ++i) {
        int e = base + i * 256;
        if (e < E) {
            int d = __builtin_nontemporal_load(&dst[e]);
            if (d >= lo && d < hi) {
                int sv = __builtin_nontemporal_load(&src[e]);
                int p = atomicAdd(&cursor[d * CSTRIDE], 1);
                if (p < d * CAP + CAP) {
                    sorted[p] = sv;
                } else {
                    int sp = atomicAdd(a.spill_n[g], 1);
                    if (sp < SPILL_CAP) {
                        a.spill[g][2 * sp] = sv;
                        a.spill[g][2 * sp + 1] = d;
                    }
                }
            }
        }
    }
}

// ---- counts + dinv from cursors ----------------------------------------------
__global__ __launch_bounds__(256) void counts_kernel(GArgs a, int g0, int n) {
    int g = g0 + blockIdx.y;
    int i = blockIdx.x * 256 + threadIdx.x;
    if (i >= n) return;
    int deg = a.cursor[g][i * CSTRIDE] - i * CAP;
    a.cstore[g][i] = min(deg, CAP);
    a.dinv[g][i] = rsqrtf((float)deg + 1.0f);
}

// ---- MFMA bf16 GEMM: Xps(bf16 row-major) = dinv[row] * (X @ W + b) -----------
__global__ __launch_bounds__(256) void gemm_kernel(GArgs a, int g0, int n) {
    int g = g0 + blockIdx.y;
    __shared__ unsigned short Xl[128 * 128];
    __shared__ unsigned short Wt[128 * 128];
    const int t = threadIdx.x;
    const int row0 = blockIdx.x * 128;
    const float* X = a.X[g];
    const float* W = a.W[g];
    char* XlB = (char*)Xl;
    char* WtB = (char*)Wt;

    for (int i = t; i < 128 * 16; i += 256) {
        int r = i >> 4, kc = i & 15;
        int row = row0 + r;
        float4 x0 = make_float4(0.f, 0.f, 0.f, 0.f), x1 = x0;
        if (row < n) {
            const float4* xp = (const float4*)(X + (size_t)row * F_DIM + kc * 8);
            x0 = xp[0]; x1 = xp[1];
        }
        uint4 pk;
        pk.x = (unsigned)f2bf(x0.x) | ((unsigned)f2bf(x0.y) << 16);
        pk.y = (unsigned)f2bf(x0.z) | ((unsigned)f2bf(x0.w) << 16);
        pk.z = (unsigned)f2bf(x1.x) | ((unsigned)f2bf(x1.y) << 16);
        pk.w = (unsigned)f2bf(x1.z) | ((unsigned)f2bf(x1.w) << 16);
        unsigned int ad = (unsigned)((r << 8) + (kc << 4)) ^ (unsigned)((r & 15) << 4);
        *(uint4*)(XlB + ad) = pk;
    }
    for (int i = t; i < 128 * 16; i += 256) {
        int nn = i & 127, kc = i >> 7;
        const float* wp = W + (size_t)(kc * 8) * F_DIM + nn;
        uint4 pk;
        pk.x = (unsigned)f2bf(wp[0])   | ((unsigned)f2bf(wp[128]) << 16);
        pk.y = (unsigned)f2bf(wp[256]) | ((unsigned)f2bf(wp[384]) << 16);
        pk.z = (unsigned)f2bf(wp[512]) | ((unsigned)f2bf(wp[640]) << 16);
        pk.w = (unsigned)f2bf(wp[768]) | ((unsigned)f2bf(wp[896]) << 16);
        unsigned int ad = (unsigned)((nn << 8) + (kc << 4)) ^ (unsigned)((nn & 15) << 4);
        *(uint4*)(WtB + ad) = pk;
    }
    __syncthreads();

    const int l = t & 63;
    const int wv = t >> 6;
    const int wr = wv >> 1, wc = wv & 1;
    const int lm = l & 15;
    const int lk = l >> 4;

    f32x4 acc[4][4] = {};
#pragma unroll
    for (int ks = 0; ks < 4; ++ks) {
        const int kb = ks * 64 + lk * 16;
        short8_t af[4], bv[4];
#pragma unroll
        for (int mt = 0; mt < 4; ++mt) {
            int r = wr * 64 + mt * 16 + lm;
            unsigned int ad = (unsigned)((r << 8) + kb) ^ (unsigned)((r & 15) << 4);
            af[mt] = *(const short8_t*)(XlB + ad);
        }
#pragma unroll
        for (int nt = 0; nt < 4; ++nt) {
            int c = wc * 64 + nt * 16 + lm;
            unsigned int ad = (unsigned)((c << 8) + kb) ^ (unsigned)((c & 15) << 4);
            bv[nt] = *(const short8_t*)(WtB + ad);
        }
#pragma unroll
        for (int mt = 0; mt < 4; ++mt)
#pragma unroll
            for (int nt = 0; nt < 4; ++nt)
                acc[mt][nt] = __builtin_amdgcn_mfma_f32_16x16x32_bf16(af[mt], bv[nt],
                                                                      acc[mt][nt], 0, 0, 0);
    }

    const float* bia = a.b[g];
    const float* dinv = a.dinv[g];
    unsigned short* Xps = a.Xps[g];
#pragma unroll
    for (int nt = 0; nt < 4; ++nt) {
        int col = wc * 64 + nt * 16 + lm;
        float bc = bia[col];
#pragma unroll
        for (int mt = 0; mt < 4; ++mt) {
            int rbase = row0 + wr * 64 + mt * 16 + lk * 4;
#pragma unroll
            for (int r = 0; r < 4; ++r) {
                int row = rbase + r;
                if (row < n) {
                    float v = (acc[mt][nt][r] + bc) * dinv[row];
                    Xps[(size_t)row * F_DIM + col] = f2bf(v);
                }
            }
        }
    }
}

// ---- aggregation: one wave per node; 8-deep batched gathers (MLP=8) ----------
__global__ __launch_bounds__(256) void agg_kernel(GArgs a, int g0, int n) {
    int g = g0 + blockIdx.y;
    int wave = (blockIdx.x * 256 + threadIdx.x) >> 6;
    if (wave >= n) return;
    int lane = threadIdx.x & 63;
    const unsigned int* Xp = (const unsigned int*)a.Xps[g];  // 64 u32 per row
    const int* sorted = a.sorted[g];
    int beg = wave * CAP;
    int cnt = a.cstore[g][wave];
    unsigned int u0 = Xp[(size_t)wave * 64 + lane];
    float ax = bflo(u0), ay = bfhi(u0);
    for (int j = 0; j < cnt;) {
        int m = min(cnt - j, 64);
        int s = (j + lane < cnt) ? __builtin_nontemporal_load(&sorted[beg + j + lane]) : 0;
        int k = 0;
        for (; k + 8 <= m; k += 8) {
            int s0 = __shfl(s, k + 0, 64), s1 = __shfl(s, k + 1, 64);
            int s2 = __shfl(s, k + 2, 64), s3 = __shfl(s, k + 3, 64);
            int s4 = __shfl(s, k + 4, 64), s5 = __shfl(s, k + 5, 64);
            int s6 = __shfl(s, k + 6, 64), s7 = __shfl(s, k + 7, 64);
            unsigned int v0 = Xp[(size_t)s0 * 64 + lane];
            unsigned int v1 = Xp[(size_t)s1 * 64 + lane];
            unsigned int v2 = Xp[(size_t)s2 * 64 + lane];
            unsigned int v3 = Xp[(size_t)s3 * 64 + lane];
            unsigned int v4 = Xp[(size_t)s4 * 64 + lane];
            unsigned int v5 = Xp[(size_t)s5 * 64 + lane];
            unsigned int v6 = Xp[(size_t)s6 * 64 + lane];
            unsigned int v7 = Xp[(size_t)s7 * 64 + lane];
            ax += bflo(v0); ay += bfhi(v0);
            ax += bflo(v1); ay += bfhi(v1);
            ax += bflo(v2); ay += bfhi(v2);
            ax += bflo(v3); ay += bfhi(v3);
            ax += bflo(v4); ay += bfhi(v4);
            ax += bflo(v5); ay += bfhi(v5);
            ax += bflo(v6); ay += bfhi(v6);
            ax += bflo(v7); ay += bfhi(v7);
        }
        if (k + 4 <= m) {
            int s0 = __shfl(s, k + 0, 64), s1 = __shfl(s, k + 1, 64);
            int s2 = __shfl(s, k + 2, 64), s3 = __shfl(s, k + 3, 64);
            unsigned int v0 = Xp[(size_t)s0 * 64 + lane];
            unsigned int v1 = Xp[(size_t)s1 * 64 + lane];
            unsigned int v2 = Xp[(size_t)s2 * 64 + lane];
            unsigned int v3 = Xp[(size_t)s3 * 64 + lane];
            ax += bflo(v0); ay += bfhi(v0);
            ax += bflo(v1); ay += bfhi(v1);
            ax += bflo(v2); ay += bfhi(v2);
            ax += bflo(v3); ay += bfhi(v3);
            k += 4;
        }
        for (; k < m; ++k) {
            int sk = __shfl(s, k, 64);
            unsigned int v = Xp[(size_t)sk * 64 + lane];
            ax += bflo(v);
            ay += bfhi(v);
        }
        j += m;
    }
    float dd = a.dinv[g][wave];
    ((float2*)a.out[g])[(size_t)wave * 64 + lane] = make_float2(ax * dd, ay * dd);
}

// ---- spill cleanup: out[d] += dinv[d] * Xps[s] for overflow edges ------------
__global__ __launch_bounds__(128) void spill_kernel(GArgs a, int g0) {
    int g = g0 + blockIdx.y;
    int ns = min(a.spill_n[g][0], SPILL_CAP);
    const unsigned short* Xps = a.Xps[g];
    const float* dinv = a.dinv[g];
    float* out = a.out[g];
    for (int i = blockIdx.x; i < ns; i += gridDim.x) {
        int s = a.spill[g][2 * i];
        int d = a.spill[g][2 * i + 1];
        float w = dinv[d];
        int f = threadIdx.x;
        float v = __uint_as_float(((unsigned int)Xps[(size_t)s * F_DIM + f]) << 16);
        unsafeAtomicAdd(&out[(size_t)d * F_DIM + f], w * v);
    }
}

extern "C" void kernel_launch(void* const* d_in, const int* in_sizes, int n_in,
                              void* d_out, int out_size, void* d_ws, size_t ws_size,
                              hipStream_t stream) {
    const float* Xin[NG] = {(const float*)d_in[0], (const float*)d_in[1], (const float*)d_in[2]};
    const int* ei[NG] = {(const int*)d_in[3], (const int*)d_in[4], (const int*)d_in[5]};
    const float* Wk[NG] = {(const float*)d_in[6], (const float*)d_in[8], (const float*)d_in[10]};
    const float* bk[NG] = {(const float*)d_in[7], (const float*)d_in[9], (const float*)d_in[11]};

    const int N = in_sizes[0] / F_DIM;  // 50000
    const int E = in_sizes[3] / 2;      // 800000
    float* out = (float*)d_out;

    const size_t xps_b = (size_t)N * F_DIM * 2;       // bf16
    const size_t sorted_b = (size_t)N * CAP * 4;
    const size_t nb = (size_t)N * 4;
    const size_t cur_b = (size_t)N * CSTRIDE * 4;     // padded cursors
    const size_t spill_b = (size_t)SPILL_CAP * 8 + 64;
    const size_t per = ((xps_b + sorted_b + cur_b + 2 * nb + spill_b + 255) / 256) * 256;
    const bool fused = ws_size >= (size_t)NG * per;
    char* base = (char*)d_ws;

    GArgs a;
    for (int r = 0; r < NG; ++r) {
        char* s = base + (size_t)(fused ? r : 0) * per;
        a.Xps[r] = (unsigned short*)s;
        a.sorted[r] = (int*)(s + xps_b);
        a.cursor[r] = (int*)(s + xps_b + sorted_b);
        a.cstore[r] = (int*)(s + xps_b + sorted_b + cur_b);
        a.dinv[r] = (float*)(s + xps_b + sorted_b + cur_b + nb);
        a.spill[r] = (int*)(s + xps_b + sorted_b + cur_b + 2 * nb);
        a.spill_n[r] = (int*)(s + xps_b + sorted_b + cur_b + 2 * nb + spill_b - 64);
        a.src[r] = ei[r];
        a.dst[r] = ei[r] + E;
        a.X[r] = Xin[r];
        a.W[r] = Wk[r];
        a.b[r] = bk[r];
        a.out[r] = out + (size_t)r * N * F_DIM;
    }

    const dim3 blk(256);
    const int nPerX = (N + XCDS - 1) / XCDS;
    const int chunks = (E + 256 * EPT - 1) / (256 * EPT);
    const int gP = chunks * XCDS;
    const int gN = (N + 255) / 256;
    const int gR = (N + 127) / 128;
    const int gA = (N * 64 + 255) / 256;

    if (fused) {
        init_kernel<<<dim3(gN, NG), blk, 0, stream>>>(a, 0, N);
        build_kernel<<<dim3(gP, NG), blk, 0, stream>>>(a, 0, E, nPerX);
        counts_kernel<<<dim3(gN, NG), blk, 0, stream>>>(a, 0, N);
        gemm_kernel<<<dim3(gR, NG), blk, 0, stream>>>(a, 0, N);
        agg_kernel<<<dim3(gA, NG), blk, 0, stream>>>(a, 0, N);
        spill_kernel<<<dim3(16, NG), dim3(128), 0, stream>>>(a, 0);
    } else {
        for (int g = 0; g < NG; ++g) {
            init_kernel<<<dim3(gN, 1), blk, 0, stream>>>(a, g, N);
            build_kernel<<<dim3(gP, 1), blk, 0, stream>>>(a, g, E, nPerX);
            counts_kernel<<<dim3(gN, 1), blk, 0, stream>>>(a, g, N);
            gemm_kernel<<<dim3(gR, 1), blk, 0, stream>>>(a, g, N);
            agg_kernel<<<dim3(gA, 1), blk, 0, stream>>>(a, g, N);
            spill_kernel<<<dim3(16, 1), dim3(128), 0, stream>>>(a, g);
        }
    }
}

// Round 13
// 194.783 us; speedup vs baseline: 1.4057x; 1.3616x over previous
//
#include <hip/hip_runtime.h>

#define F_DIM 128
#define NG 3
#define AEPT 16      // edges per thread in phase A
#define CAP 48       // fixed per-node CSR capacity (mean deg 16, max ~35)
#define MAXBIN 256
#define SPILL_CAP 8192

typedef __attribute__((ext_vector_type(8))) short short8_t;
typedef __attribute__((ext_vector_type(4))) float f32x4;

__device__ __forceinline__ unsigned short f2bf(float f) {
    unsigned int x = __float_as_uint(f);
    unsigned int r = x + 0x7fffu + ((x >> 16) & 1u);  // RNE
    return (unsigned short)(r >> 16);
}
__device__ __forceinline__ float bflo(unsigned int u) { return __uint_as_float(u << 16); }
__device__ __forceinline__ float bfhi(unsigned int u) { return __uint_as_float(u & 0xffff0000u); }

struct GArgs {
    const int* src[NG]; const int* dst[NG];
    const float* X[NG]; const float* W[NG]; const float* b[NG];
    float* out[NG];
    unsigned short* Xps[NG];   // bf16 row-major [N][128], pre-scaled by dinv[row]
    unsigned short* sorted[NG];// [N*CAP] u16 src indices
    int* binbuf[NG];           // [nbin*BINCAP] packed (dlocal<<16)|src
    int* bincur[NG];           // [nbin] global bin cursors (init bin*BINCAP)
    int* cstore[NG];           // [N] stored counts (<=CAP)
    float* dinv[NG];           // [N]
    int* spill[NG];            // [SPILL_CAP*2] (src,dst) pairs
    int* spill_n[NG];          // [1]
    int nbin, bincap;
};

// ---- init: bincur[i] = i*BINCAP; spill_n = 0 ---------------------------------
__global__ __launch_bounds__(256) void init_kernel(GArgs a, int g0) {
    int g = g0 + blockIdx.y;
    for (int i = threadIdx.x; i < a.nbin; i += 256) a.bincur[g][i] = i * a.bincap;
    if (threadIdx.x == 0) a.spill_n[g][0] = 0;
}

// ---- phase A: coarse radix partition (bin = dst>>8), LDS counting ------------
// One global atomic per (block,bin) instead of per edge; edges read ONCE.
__global__ __launch_bounds__(256) void binA_kernel(GArgs a, int g0, int E) {
    int g = g0 + blockIdx.y;
    __shared__ int cnt[MAXBIN];
    __shared__ int lcur[MAXBIN];
    const int t = threadIdx.x;
    const int nbin = a.nbin, bincap = a.bincap;
    for (int i = t; i < nbin; i += 256) cnt[i] = 0;
    __syncthreads();
    const int* dst = a.dst[g];
    const int* src = a.src[g];
    const int base = blockIdx.x * (256 * AEPT) + t;
    int dd[AEPT], sv[AEPT];
#pragma unroll
    for (int i = 0; i < AEPT; ++i) {
        int e = base + i * 256;
        int ec = (e < E) ? e : 0;
        dd[i] = __builtin_nontemporal_load(&dst[ec]);
        sv[i] = __builtin_nontemporal_load(&src[ec]);
        if (e < E) atomicAdd(&cnt[dd[i] >> 8], 1);
    }
    __syncthreads();
    for (int i = t; i < nbin; i += 256) {
        int c = cnt[i];
        lcur[i] = c ? atomicAdd(&a.bincur[g][i], c) : 0;
    }
    __syncthreads();
    int* binbuf = a.binbuf[g];
#pragma unroll
    for (int i = 0; i < AEPT; ++i) {
        int e = base + i * 256;
        if (e < E) {
            int bin = dd[i] >> 8;
            int pos = atomicAdd(&lcur[bin], 1);
            if (pos < (bin + 1) * bincap) {
                binbuf[pos] = ((dd[i] & 255) << 16) | sv[i];
            } else {
                int sp = atomicAdd(a.spill_n[g], 1);
                if (sp < SPILL_CAP) {
                    a.spill[g][2 * sp] = sv[i];
                    a.spill[g][2 * sp + 1] = dd[i];
                }
            }
        }
    }
}

// ---- phase B: fine binning within a bin; LDS tickets only, no global atomics -
// Also emits exact cstore + dinv (replaces counts_kernel).
__global__ __launch_bounds__(256) void binB_kernel(GArgs a, int g0, int n) {
    int g = g0 + blockIdx.y;
    int bin = blockIdx.x;
    const int t = threadIdx.x;
    __shared__ int cnt[256];
    cnt[t] = 0;
    __syncthreads();
    const int bincap = a.bincap;
    int used = a.bincur[g][bin] - bin * bincap;
    int rd = min(used, bincap);
    const int* bb = a.binbuf[g] + bin * bincap;
    unsigned short* sorted = a.sorted[g];
    for (int j = t; j < rd; j += 256) {
        int u = bb[j];
        int dl = u >> 16;
        int s = u & 0xffff;
        int tk = atomicAdd(&cnt[dl], 1);
        int d = (bin << 8) + dl;
        if (tk < CAP) {
            sorted[d * CAP + tk] = (unsigned short)s;
        } else {
            int sp = atomicAdd(a.spill_n[g], 1);
            if (sp < SPILL_CAP) {
                a.spill[g][2 * sp] = s;
                a.spill[g][2 * sp + 1] = d;
            }
        }
    }
    __syncthreads();
    int d = (bin << 8) + t;
    if (d < n) {
        int deg = cnt[t];
        a.cstore[g][d] = min(deg, CAP);
        a.dinv[g][d] = rsqrtf((float)deg + 1.0f);
    }
}

// ---- MFMA bf16 GEMM: Xps(bf16 row-major) = dinv[row] * (X @ W + b) -----------
__global__ __launch_bounds__(256) void gemm_kernel(GArgs a, int g0, int n) {
    int g = g0 + blockIdx.y;
    __shared__ unsigned short Xl[128 * 128];
    __shared__ unsigned short Wt[128 * 128];
    const int t = threadIdx.x;
    const int row0 = blockIdx.x * 128;
    const float* X = a.X[g];
    const float* W = a.W[g];
    char* XlB = (char*)Xl;
    char* WtB = (char*)Wt;

    for (int i = t; i < 128 * 16; i += 256) {
        int r = i >> 4, kc = i & 15;
        int row = row0 + r;
        float4 x0 = make_float4(0.f, 0.f, 0.f, 0.f), x1 = x0;
        if (row < n) {
            const float4* xp = (const float4*)(X + (size_t)row * F_DIM + kc * 8);
            x0 = xp[0]; x1 = xp[1];
        }
        uint4 pk;
        pk.x = (unsigned)f2bf(x0.x) | ((unsigned)f2bf(x0.y) << 16);
        pk.y = (unsigned)f2bf(x0.z) | ((unsigned)f2bf(x0.w) << 16);
        pk.z = (unsigned)f2bf(x1.x) | ((unsigned)f2bf(x1.y) << 16);
        pk.w = (unsigned)f2bf(x1.z) | ((unsigned)f2bf(x1.w) << 16);
        unsigned int ad = (unsigned)((r << 8) + (kc << 4)) ^ (unsigned)((r & 15) << 4);
        *(uint4*)(XlB + ad) = pk;
    }
    for (int i = t; i < 128 * 16; i += 256) {
        int nn = i & 127, kc = i >> 7;
        const float* wp = W + (size_t)(kc * 8) * F_DIM + nn;
        uint4 pk;
        pk.x = (unsigned)f2bf(wp[0])   | ((unsigned)f2bf(wp[128]) << 16);
        pk.y = (unsigned)f2bf(wp[256]) | ((unsigned)f2bf(wp[384]) << 16);
        pk.z = (unsigned)f2bf(wp[512]) | ((unsigned)f2bf(wp[640]) << 16);
        pk.w = (unsigned)f2bf(wp[768]) | ((unsigned)f2bf(wp[896]) << 16);
        unsigned int ad = (unsigned)((nn << 8) + (kc << 4)) ^ (unsigned)((nn & 15) << 4);
        *(uint4*)(WtB + ad) = pk;
    }
    __syncthreads();

    const int l = t & 63;
    const int wv = t >> 6;
    const int wr = wv >> 1, wc = wv & 1;
    const int lm = l & 15;
    const int lk = l >> 4;

    f32x4 acc[4][4] = {};
#pragma unroll
    for (int ks = 0; ks < 4; ++ks) {
        const int kb = ks * 64 + lk * 16;
        short8_t af[4], bv[4];
#pragma unroll
        for (int mt = 0; mt < 4; ++mt) {
            int r = wr * 64 + mt * 16 + lm;
            unsigned int ad = (unsigned)((r << 8) + kb) ^ (unsigned)((r & 15) << 4);
            af[mt] = *(const short8_t*)(XlB + ad);
        }
#pragma unroll
        for (int nt = 0; nt < 4; ++nt) {
            int c = wc * 64 + nt * 16 + lm;
            unsigned int ad = (unsigned)((c << 8) + kb) ^ (unsigned)((c & 15) << 4);
            bv[nt] = *(const short8_t*)(WtB + ad);
        }
#pragma unroll
        for (int mt = 0; mt < 4; ++mt)
#pragma unroll
            for (int nt = 0; nt < 4; ++nt)
                acc[mt][nt] = __builtin_amdgcn_mfma_f32_16x16x32_bf16(af[mt], bv[nt],
                                                                      acc[mt][nt], 0, 0, 0);
    }

    const float* bia = a.b[g];
    const float* dinv = a.dinv[g];
    unsigned short* Xps = a.Xps[g];
#pragma unroll
    for (int nt = 0; nt < 4; ++nt) {
        int col = wc * 64 + nt * 16 + lm;
        float bc = bia[col];
#pragma unroll
        for (int mt = 0; mt < 4; ++mt) {
            int rbase = row0 + wr * 64 + mt * 16 + lk * 4;
#pragma unroll
            for (int r = 0; r < 4; ++r) {
                int row = rbase + r;
                if (row < n) {
                    float v = (acc[mt][nt][r] + bc) * dinv[row];
                    Xps[(size_t)row * F_DIM + col] = f2bf(v);
                }
            }
        }
    }
}

// ---- aggregation: one wave per node; 8-deep batched gathers; u16 sorted ------
__global__ __launch_bounds__(256) void agg_kernel(GArgs a, int g0, int n) {
    int g = g0 + blockIdx.y;
    int wave = (blockIdx.x * 256 + threadIdx.x) >> 6;
    if (wave >= n) return;
    int lane = threadIdx.x & 63;
    const unsigned int* Xp = (const unsigned int*)a.Xps[g];  // 64 u32 per row
    const unsigned short* sorted = a.sorted[g];
    int beg = wave * CAP;
    int cnt = a.cstore[g][wave];
    unsigned int u0 = Xp[(size_t)wave * 64 + lane];
    float ax = bflo(u0), ay = bfhi(u0);
    for (int j = 0; j < cnt;) {
        int m = min(cnt - j, 64);
        int s = (j + lane < cnt)
                    ? (int)__builtin_nontemporal_load(&sorted[beg + j + lane]) : 0;
        int k = 0;
        for (; k + 8 <= m; k += 8) {
            int s0 = __shfl(s, k + 0, 64), s1 = __shfl(s, k + 1, 64);
            int s2 = __shfl(s, k + 2, 64), s3 = __shfl(s, k + 3, 64);
            int s4 = __shfl(s, k + 4, 64), s5 = __shfl(s, k + 5, 64);
            int s6 = __shfl(s, k + 6, 64), s7 = __shfl(s, k + 7, 64);
            unsigned int v0 = Xp[(size_t)s0 * 64 + lane];
            unsigned int v1 = Xp[(size_t)s1 * 64 + lane];
            unsigned int v2 = Xp[(size_t)s2 * 64 + lane];
            unsigned int v3 = Xp[(size_t)s3 * 64 + lane];
            unsigned int v4 = Xp[(size_t)s4 * 64 + lane];
            unsigned int v5 = Xp[(size_t)s5 * 64 + lane];
            unsigned int v6 = Xp[(size_t)s6 * 64 + lane];
            unsigned int v7 = Xp[(size_t)s7 * 64 + lane];
            ax += bflo(v0); ay += bfhi(v0);
            ax += bflo(v1); ay += bfhi(v1);
            ax += bflo(v2); ay += bfhi(v2);
            ax += bflo(v3); ay += bfhi(v3);
            ax += bflo(v4); ay += bfhi(v4);
            ax += bflo(v5); ay += bfhi(v5);
            ax += bflo(v6); ay += bfhi(v6);
            ax += bflo(v7); ay += bfhi(v7);
        }
        if (k + 4 <= m) {
            int s0 = __shfl(s, k + 0, 64), s1 = __shfl(s, k + 1, 64);
            int s2 = __shfl(s, k + 2, 64), s3 = __shfl(s, k + 3, 64);
            unsigned int v0 = Xp[(size_t)s0 * 64 + lane];
            unsigned int v1 = Xp[(size_t)s1 * 64 + lane];
            unsigned int v2 = Xp[(size_t)s2 * 64 + lane];
            unsigned int v3 = Xp[(size_t)s3 * 64 + lane];
            ax += bflo(v0); ay += bfhi(v0);
            ax += bflo(v1); ay += bfhi(v1);
            ax += bflo(v2); ay += bfhi(v2);
            ax += bflo(v3); ay += bfhi(v3);
            k += 4;
        }
        for (; k < m; ++k) {
            int sk = __shfl(s, k, 64);
            unsigned int v = Xp[(size_t)sk * 64 + lane];
            ax += bflo(v);
            ay += bfhi(v);
        }
        j += m;
    }
    float dd = a.dinv[g][wave];
    ((float2*)a.out[g])[(size_t)wave * 64 + lane] = make_float2(ax * dd, ay * dd);
}

// ---- spill cleanup: out[d] += dinv[d] * Xps[s] for overflow edges ------------
__global__ __launch_bounds__(128) void spill_kernel(GArgs a, int g0) {
    int g = g0 + blockIdx.y;
    int ns = min(a.spill_n[g][0], SPILL_CAP);
    const unsigned short* Xps = a.Xps[g];
    const float* dinv = a.dinv[g];
    float* out = a.out[g];
    for (int i = blockIdx.x; i < ns; i += gridDim.x) {
        int s = a.spill[g][2 * i];
        int d = a.spill[g][2 * i + 1];
        float w = dinv[d];
        int f = threadIdx.x;
        float v = __uint_as_float(((unsigned int)Xps[(size_t)s * F_DIM + f]) << 16);
        unsafeAtomicAdd(&out[(size_t)d * F_DIM + f], w * v);
    }
}

extern "C" void kernel_launch(void* const* d_in, const int* in_sizes, int n_in,
                              void* d_out, int out_size, void* d_ws, size_t ws_size,
                              hipStream_t stream) {
    const float* Xin[NG] = {(const float*)d_in[0], (const float*)d_in[1], (const float*)d_in[2]};
    const int* ei[NG] = {(const int*)d_in[3], (const int*)d_in[4], (const int*)d_in[5]};
    const float* Wk[NG] = {(const float*)d_in[6], (const float*)d_in[8], (const float*)d_in[10]};
    const float* bk[NG] = {(const float*)d_in[7], (const float*)d_in[9], (const float*)d_in[11]};

    const int N = in_sizes[0] / F_DIM;  // 50000
    const int E = in_sizes[3] / 2;      // 800000
    float* out = (float*)d_out;

    const int nbin = (N + 255) >> 8;                    // 196
    const int bincap = E / nbin + E / (3 * nbin) + 256; // ~5700 (mean+33%+256)

    const size_t xps_b = (size_t)N * F_DIM * 2;         // bf16
    const size_t sorted_b = (size_t)N * CAP * 2;        // u16
    const size_t binbuf_b = (size_t)nbin * bincap * 4;
    const size_t nb = (size_t)N * 4;
    const size_t bincur_b = ((size_t)nbin * 4 + 255) / 256 * 256;
    const size_t spill_b = (size_t)SPILL_CAP * 8 + 64;
    const size_t per = ((xps_b + sorted_b + binbuf_b + 2 * nb + bincur_b + spill_b + 255)
                        / 256) * 256;
    const bool fused = ws_size >= (size_t)NG * per;
    char* base = (char*)d_ws;

    GArgs a;
    a.nbin = nbin;
    a.bincap = bincap;
    for (int r = 0; r < NG; ++r) {
        char* s = base + (size_t)(fused ? r : 0) * per;
        size_t off = 0;
        a.Xps[r] = (unsigned short*)(s + off); off += xps_b;
        a.sorted[r] = (unsigned short*)(s + off); off += sorted_b;
        a.binbuf[r] = (int*)(s + off); off += binbuf_b;
        a.cstore[r] = (int*)(s + off); off += nb;
        a.dinv[r] = (float*)(s + off); off += nb;
        a.bincur[r] = (int*)(s + off); off += bincur_b;
        a.spill[r] = (int*)(s + off);
        a.spill_n[r] = (int*)(s + off + spill_b - 64);
        a.src[r] = ei[r];
        a.dst[r] = ei[r] + E;
        a.X[r] = Xin[r];
        a.W[r] = Wk[r];
        a.b[r] = bk[r];
        a.out[r] = out + (size_t)r * N * F_DIM;
    }

    const dim3 blk(256);
    const int gAe = (E + 256 * AEPT - 1) / (256 * AEPT);  // phase A blocks
    const int gR = (N + 127) / 128;
    const int gG = (N * 64 + 255) / 256;

    if (fused) {
        init_kernel<<<dim3(1, NG), blk, 0, stream>>>(a, 0);
        binA_kernel<<<dim3(gAe, NG), blk, 0, stream>>>(a, 0, E);
        binB_kernel<<<dim3(nbin, NG), blk, 0, stream>>>(a, 0, N);
        gemm_kernel<<<dim3(gR, NG), blk, 0, stream>>>(a, 0, N);
        agg_kernel<<<dim3(gG, NG), blk, 0, stream>>>(a, 0, N);
        spill_kernel<<<dim3(16, NG), dim3(128), 0, stream>>>(a, 0);
    } else {
        for (int g = 0; g < NG; ++g) {
            init_kernel<<<dim3(1, 1), blk, 0, stream>>>(a, g);
            binA_kernel<<<dim3(gAe, 1), blk, 0, stream>>>(a, g, E);
            binB_kernel<<<dim3(nbin, 1), blk, 0, stream>>>(a, g, N);
            gemm_kernel<<<dim3(gR, 1), blk, 0, stream>>>(a, g, N);
            agg_kernel<<<dim3(gG, 1), blk, 0, stream>>>(a, g, N);
            spill_kernel<<<dim3(16, 1), dim3(128), 0, stream>>>(a, g);
        }
    }
}